// Round 2
// baseline (384.490 us; speedup 1.0000x reference)
//
#include <hip/hip_runtime.h>

// B=16, H=8, N=64, L=64, DK=64  -> 8192 instances of 64x64x64 attention.
// One 256-thread block (4 waves) per instance. fp32 in/out.
// QK^T: split-bf16 (hi+lo) MFMA for ~fp32 logit accuracy; PV: bf16 MFMA.

typedef short short8 __attribute__((ext_vector_type(8)));
typedef float f32x4 __attribute__((ext_vector_type(4)));
typedef unsigned short u16;
typedef unsigned int   u32;
typedef unsigned long long u64;

// XOR swizzle (guide G4): element index within a [rows][64] bf16 tile.
// byte ^= ((row&7)<<4)  ==  elem ^= ((row&7)<<3). Keeps 8-elem (16B) groups intact.
__device__ __forceinline__ int SW(int r, int c) { return r * 64 + (c ^ ((r & 7) << 3)); }

__device__ __forceinline__ u16 f2bf(float f) {            // RNE fp32->bf16
  u32 u = __float_as_uint(f);
  return (u16)((u + 0x7fffu + ((u >> 16) & 1u)) >> 16);
}
__device__ __forceinline__ float bf2f(u16 b) { return __uint_as_float(((u32)b) << 16); }

__global__ __launch_bounds__(256, 3)
void attn64_kernel(const float* __restrict__ qg, const float* __restrict__ kg,
                   const float* __restrict__ vg, const int* __restrict__ mg,
                   float* __restrict__ og)
{
  __shared__ u16 qh_l[4096], ql_l[4096], kh_l[4096], kl_l[4096];
  __shared__ u16 vt_l[4096];          // V transposed: vt[d][kk]
  __shared__ u16 p_l[4096];           // per-wave 16x64 P strips
  __shared__ u64 mb_l[64];            // mask bitmask, one u64 per q-row

  const int inst = blockIdx.x;        // (b,h,n) flattened
  const int b    = inst >> 9;         // / (H*N) = /512
  const long base = (long)inst << 12; // *4096
  const int tid  = threadIdx.x;

  // ---------------- stage: global fp32 -> LDS bf16 (swizzled) ----------------
  {
    const int r  = tid >> 2;            // 0..63
    const int c0 = (tid & 3) << 4;      // 0,16,32,48
    const f32x4* qrow = (const f32x4*)(qg + base + r * 64 + c0);
    const f32x4* krow = (const f32x4*)(kg + base + r * 64 + c0);
#pragma unroll
    for (int j = 0; j < 4; ++j) {
      f32x4 fq = qrow[j];
      f32x4 fk = krow[j];
      const int c = c0 + 4 * j;
      u16 h0 = f2bf(fq[0]), h1 = f2bf(fq[1]), h2 = f2bf(fq[2]), h3 = f2bf(fq[3]);
      *(u32*)&qh_l[SW(r, c)]     = (u32)h0 | ((u32)h1 << 16);
      *(u32*)&qh_l[SW(r, c + 2)] = (u32)h2 | ((u32)h3 << 16);
      u16 e0 = f2bf(fq[0] - bf2f(h0)), e1 = f2bf(fq[1] - bf2f(h1));
      u16 e2 = f2bf(fq[2] - bf2f(h2)), e3 = f2bf(fq[3] - bf2f(h3));
      *(u32*)&ql_l[SW(r, c)]     = (u32)e0 | ((u32)e1 << 16);
      *(u32*)&ql_l[SW(r, c + 2)] = (u32)e2 | ((u32)e3 << 16);
      h0 = f2bf(fk[0]); h1 = f2bf(fk[1]); h2 = f2bf(fk[2]); h3 = f2bf(fk[3]);
      *(u32*)&kh_l[SW(r, c)]     = (u32)h0 | ((u32)h1 << 16);
      *(u32*)&kh_l[SW(r, c + 2)] = (u32)h2 | ((u32)h3 << 16);
      e0 = f2bf(fk[0] - bf2f(h0)); e1 = f2bf(fk[1] - bf2f(h1));
      e2 = f2bf(fk[2] - bf2f(h2)); e3 = f2bf(fk[3] - bf2f(h3));
      *(u32*)&kl_l[SW(r, c)]     = (u32)e0 | ((u32)e1 << 16);
      *(u32*)&kl_l[SW(r, c + 2)] = (u32)e2 | ((u32)e3 << 16);
    }
    // mask bitmask: thread builds 16 bits of row r
    const int4* mrow = (const int4*)(mg + (long)b * 4096 + r * 64 + c0);
    u32 bits = 0;
#pragma unroll
    for (int j = 0; j < 4; ++j) {
      int4 mm = mrow[j];
      bits |= (mm.x != 0 ? 1u : 0u) << (4 * j + 0);
      bits |= (mm.y != 0 ? 1u : 0u) << (4 * j + 1);
      bits |= (mm.z != 0 ? 1u : 0u) << (4 * j + 2);
      bits |= (mm.w != 0 ? 1u : 0u) << (4 * j + 3);
    }
    ((u16*)mb_l)[r * 4 + (tid & 3)] = (u16)bits;

    // V transposed: thread covers kk=[kk0,kk0+4) x d=[d0,d0+4)
    const int kk0 = (tid & 15) << 2;
    const int d0  = (tid >> 4) << 2;
    f32x4 v0 = *(const f32x4*)(vg + base + (kk0 + 0) * 64 + d0);
    f32x4 v1 = *(const f32x4*)(vg + base + (kk0 + 1) * 64 + d0);
    f32x4 v2 = *(const f32x4*)(vg + base + (kk0 + 2) * 64 + d0);
    f32x4 v3 = *(const f32x4*)(vg + base + (kk0 + 3) * 64 + d0);
#pragma unroll
    for (int jd = 0; jd < 4; ++jd) {
      const int d = d0 + jd;
      u32 w0 = (u32)f2bf(v0[jd]) | ((u32)f2bf(v1[jd]) << 16);
      u32 w1 = (u32)f2bf(v2[jd]) | ((u32)f2bf(v3[jd]) << 16);
      u32* dst = (u32*)&vt_l[SW(d, kk0)];
      dst[0] = w0; dst[1] = w1;
    }
  }
  __syncthreads();

  // ---------------- per-wave compute: 16-row output strip ----------------
  const int lane = tid & 63;
  const int wv   = tid >> 6;     // wave id 0..3 -> rows [16wv,16wv+16)
  const int g    = lane >> 4;    // 0..3
  const int cl   = lane & 15;

  f32x4 accS[4];
#pragma unroll
  for (int t = 0; t < 4; ++t) accS[t] = f32x4{0.f, 0.f, 0.f, 0.f};

  // S = Q K^T via split bf16: q*k ~= qh*kh + ql*kh + qh*kl
#pragma unroll
  for (int ks = 0; ks < 2; ++ks) {
    const int kc = g * 8 + ks * 32;
    short8 aH = *(const short8*)&qh_l[SW(wv * 16 + cl, kc)];
    short8 aL = *(const short8*)&ql_l[SW(wv * 16 + cl, kc)];
#pragma unroll
    for (int t = 0; t < 4; ++t) {
      short8 bH = *(const short8*)&kh_l[SW(t * 16 + cl, kc)];
      short8 bL = *(const short8*)&kl_l[SW(t * 16 + cl, kc)];
      accS[t] = __builtin_amdgcn_mfma_f32_16x16x32_bf16(aH, bH, accS[t], 0, 0, 0);
      accS[t] = __builtin_amdgcn_mfma_f32_16x16x32_bf16(aL, bH, accS[t], 0, 0, 0);
      accS[t] = __builtin_amdgcn_mfma_f32_16x16x32_bf16(aH, bL, accS[t], 0, 0, 0);
    }
  }

  // masked softmax in C-fragment layout (row=g*4+r, col=cl+16t), exp2 domain
  const float SCL  = 0.125f * 1.44269504088896340736f;    // log2(e)/TEMPERATURE
  const float NEGB = -32768.0f * 1.44269504088896340736f; // MASK_FILL*log2(e)
  float rinv[4];
  u16* pw = &p_l[wv * 1024];
#pragma unroll
  for (int r = 0; r < 4; ++r) {
    const int rr = g * 4 + r;                       // strip-local q row
    u64 m64 = mb_l[wv * 16 + rr] >> cl;
    u32 mlo = (u32)m64, mhi = (u32)(m64 >> 32);
    float y0 = (mlo & 1u)       ? accS[0][r] * SCL : NEGB;
    float y1 = (mlo & 0x10000u) ? accS[1][r] * SCL : NEGB;
    float y2 = (mhi & 1u)       ? accS[2][r] * SCL : NEGB;
    float y3 = (mhi & 0x10000u) ? accS[3][r] * SCL : NEGB;
    float m = fmaxf(fmaxf(y0, y1), fmaxf(y2, y3));
#pragma unroll
    for (int s = 1; s < 16; s <<= 1) m = fmaxf(m, __shfl_xor(m, s, 64));
    float p0 = exp2f(y0 - m), p1 = exp2f(y1 - m);
    float p2 = exp2f(y2 - m), p3 = exp2f(y3 - m);
    float sum = (p0 + p1) + (p2 + p3);
#pragma unroll
    for (int s = 1; s < 16; s <<= 1) sum += __shfl_xor(sum, s, 64);
    rinv[r] = 1.0f / sum;
    const int rbase = rr * 64;
    const int sx = (rr & 7) << 3;
    pw[rbase + ((cl)      ^ sx)] = f2bf(p0);
    pw[rbase + ((cl + 16) ^ sx)] = f2bf(p1);
    pw[rbase + ((cl + 32) ^ sx)] = f2bf(p2);
    pw[rbase + ((cl + 48) ^ sx)] = f2bf(p3);
  }
  __syncthreads();  // LDS fence; also keeps compiler from reordering p writes/reads

  // O = P V
  f32x4 accO[4];
#pragma unroll
  for (int t = 0; t < 4; ++t) accO[t] = f32x4{0.f, 0.f, 0.f, 0.f};
#pragma unroll
  for (int ks = 0; ks < 2; ++ks) {
    const int kc = g * 8 + ks * 32;
    short8 pa = *(const short8*)&pw[SW(cl, kc)];
#pragma unroll
    for (int t = 0; t < 4; ++t) {
      short8 vb = *(const short8*)&vt_l[SW(t * 16 + cl, kc)];
      accO[t] = __builtin_amdgcn_mfma_f32_16x16x32_bf16(pa, vb, accO[t], 0, 0, 0);
    }
  }

  // epilogue: normalize rows, store fp32
  float* orow = og + base;
#pragma unroll
  for (int t = 0; t < 4; ++t) {
#pragma unroll
    for (int r = 0; r < 4; ++r) {
      const int q = wv * 16 + g * 4 + r;
      orow[q * 64 + t * 16 + cl] = accO[t][r] * rinv[r];
    }
  }
}

extern "C" void kernel_launch(void* const* d_in, const int* in_sizes, int n_in,
                              void* d_out, int out_size, void* d_ws, size_t ws_size,
                              hipStream_t stream) {
  const float* q = (const float*)d_in[0];
  const float* k = (const float*)d_in[1];
  const float* v = (const float*)d_in[2];
  const int*   m = (const int*)d_in[3];
  float* out = (float*)d_out;
  const int instances = in_sizes[0] >> 12;  // B*H*N = 8192
  attn64_kernel<<<dim3(instances), dim3(256), 0, stream>>>(q, k, v, m, out);
}